// Round 1
// baseline (65.413 us; speedup 1.0000x reference)
//
#include <hip/hip_runtime.h>

#define NUM_ROWS 500000
#define TERMS 164
#define KSTEPS 6            // 6 * 32 = 192 >= 164 (zero padded)
#define TILES (NUM_ROWS / 16)   // 31250 exactly

typedef __attribute__((ext_vector_type(8))) short bf16x8;
typedef __attribute__((ext_vector_type(4))) float f32x4;
typedef __attribute__((ext_vector_type(4))) unsigned int uint4v;

// ---------------------------------------------------------------------------
// Compile-time replica of the reference exponent-table construction.
// comb = np.array(np.meshgrid(*([0..3]*8))).T.reshape(-1,8); keep 1<=sum<=3.
// Row order r = lexicographic over digits (b0..b7), and
// comb[r] = (b6, b7, b5, b4, b3, b2, b1, b0)  =>  r-order == lex order of
// the key (e7, e6, e5, e4, e3, e2, e0, e1).
// ---------------------------------------------------------------------------
struct ETab { int e[192][8]; int n; };

constexpr ETab make_et() {
    ETab T{};
    for (int i = 0; i < 192; ++i)
        for (int f = 0; f < 8; ++f) T.e[i][f] = 0;
    T.n = 0;
    for (int a = 0; a <= 3; ++a)                       // e7
     for (int b = 0; a + b <= 3; ++b)                  // e6
      for (int c = 0; a + b + c <= 3; ++c)             // e5
       for (int d = 0; a + b + c + d <= 3; ++d)        // e4
        for (int e_ = 0; a + b + c + d + e_ <= 3; ++e_)            // e3
         for (int f_ = 0; a + b + c + d + e_ + f_ <= 3; ++f_)      // e2
          for (int g = 0; a + b + c + d + e_ + f_ + g <= 3; ++g)   // e0
           for (int h = 0; a + b + c + d + e_ + f_ + g + h <= 3; ++h) { // e1
               int s = a + b + c + d + e_ + f_ + g + h;
               if (s >= 1) {
                   T.e[T.n][0] = g;  T.e[T.n][1] = h;
                   T.e[T.n][2] = f_; T.e[T.n][3] = e_;
                   T.e[T.n][4] = d;  T.e[T.n][5] = c;
                   T.e[T.n][6] = b;  T.e[T.n][7] = a;
                   ++T.n;
               }
           }
    return T;
}

static_assert(make_et().n == TERMS, "term count must be 164");
__device__ constexpr ETab ET = make_et();

// RNE float -> bf16 (finite inputs), packs two bf16 into one dword.
__device__ __forceinline__ unsigned int pack2bf(float a, float b) {
    unsigned int ua = __float_as_uint(a), ub = __float_as_uint(b);
    ua = ua + 0x7fffu + ((ua >> 16) & 1u);
    ub = ub + 0x7fffu + ((ub >> 16) & 1u);
    return (ua >> 16) | (ub & 0xffff0000u);
}

// Term value; t is compile-time constant after full unrolling, so the ET
// loads and the degree branches fold away (<=2 v_mul_f32 per term).
// Multiplication order matches the reference (f ascending, start at 1.0f;
// x*1.0f is exact so folding is value-preserving).
__device__ __forceinline__ float term_val(int t, const float (&p1)[8],
                                          const float (&p2)[8],
                                          const float (&p3)[8]) {
    if (t >= TERMS) return 0.f;
    float v = 1.f;
#pragma unroll
    for (int f = 0; f < 8; ++f) {
        const int d = ET.e[t][f];
        if (d == 1) v *= p1[f];
        else if (d == 2) v *= p2[f];
        else if (d == 3) v *= p3[f];
    }
    return v;
}

__global__ __launch_bounds__(256) void poly_mfma_kernel(
        const float* __restrict__ x,       // [500000, 8]
        const float* __restrict__ weight,  // [64, 164]
        const float* __restrict__ bias,    // [64]
        float* __restrict__ out)           // [500000, 64]
{
    // B fragments (weight^T as bf16) staged once per block in exact MFMA
    // B-operand order: frag p = ks*4+nt, per lane 8 bf16 (4 dwords).
    __shared__ unsigned int sB[KSTEPS * 4 * 64 * 4];   // 24 KiB

    const int tid = threadIdx.x;
#pragma unroll 1
    for (int idx = tid; idx < KSTEPS * 4 * 64 * 4; idx += 256) {
        int p    = idx >> 8;          // fragment 0..23
        int lane = (idx >> 2) & 63;
        int dw   = idx & 3;
        int ks   = p >> 2;
        int nt   = p & 3;
        int kq   = lane >> 4;
        int j    = (nt << 4) | (lane & 15);          // output column 0..63
        int t0   = ks * 32 + kq * 8 + dw * 2;        // term index (k)
        float f0 = (t0     < TERMS) ? weight[j * TERMS + t0]     : 0.f;
        float f1 = (t0 + 1 < TERMS) ? weight[j * TERMS + t0 + 1] : 0.f;
        sB[idx] = pack2bf(f0, f1);
    }
    __syncthreads();

    const int lane = tid & 63;
    const int wid  = tid >> 6;
    const int m    = lane & 15;   // A row within tile / D column within ntile
    const int kq   = lane >> 4;   // k-quarter

    float bcol[4];
#pragma unroll
    for (int nt = 0; nt < 4; ++nt) bcol[nt] = bias[nt * 16 + m];

    const int gwave  = blockIdx.x * 4 + wid;
    const int nwaves = gridDim.x * 4;
    const uint4v* sB4 = (const uint4v*)sB;

    for (int tile = gwave; tile < TILES; tile += nwaves) {
        // ---- load this lane's row of x, build power table (fp32-exact) ----
        const int row = tile * 16 + m;
        const float4* xp = (const float4*)(x + row * 8);
        float4 xa = xp[0];
        float4 xb = xp[1];
        float p1[8], p2[8], p3[8];
        p1[0] = xa.x; p1[1] = xa.y; p1[2] = xa.z; p1[3] = xa.w;
        p1[4] = xb.x; p1[5] = xb.y; p1[6] = xb.z; p1[7] = xb.w;
#pragma unroll
        for (int f = 0; f < 8; ++f) {
            p2[f] = p1[f] * p1[f];        // == cumprod step 2
            p3[f] = p2[f] * p1[f];        // == cumprod step 3
        }

        f32x4 acc[4];
#pragma unroll
        for (int nt = 0; nt < 4; ++nt) acc[nt] = (f32x4){0.f, 0.f, 0.f, 0.f};

#pragma unroll
        for (int ks = 0; ks < KSTEPS; ++ks) {
            // ---- build A fragment: element e -> term ks*32 + kq*8 + e ----
            unsigned int ad[4];
#pragma unroll
            for (int e2 = 0; e2 < 4; ++e2) {
                float vv[2];
#pragma unroll
                for (int half = 0; half < 2; ++half) {
                    const int e = e2 * 2 + half;
                    float q0 = term_val(ks * 32 +  0 + e, p1, p2, p3);
                    float q1 = term_val(ks * 32 +  8 + e, p1, p2, p3);
                    float q2 = term_val(ks * 32 + 16 + e, p1, p2, p3);
                    float q3 = term_val(ks * 32 + 24 + e, p1, p2, p3);
                    float v01 = (kq & 1) ? q1 : q0;
                    float v23 = (kq & 1) ? q3 : q2;
                    vv[half] = (kq & 2) ? v23 : v01;
                }
                ad[e2] = pack2bf(vv[0], vv[1]);
            }
            uint4v av = {ad[0], ad[1], ad[2], ad[3]};
            bf16x8 afrag = __builtin_bit_cast(bf16x8, av);

#pragma unroll
            for (int nt = 0; nt < 4; ++nt) {
                uint4v bw = sB4[(ks * 4 + nt) * 64 + lane];
                bf16x8 bfrag = __builtin_bit_cast(bf16x8, bw);
                acc[nt] = __builtin_amdgcn_mfma_f32_16x16x32_bf16(
                              afrag, bfrag, acc[nt], 0, 0, 0);
            }
        }

        // ---- epilogue: D element (reg r, lane) -> row kq*4+r, col nt*16+m
        const int rbase = tile * 16 + kq * 4;
#pragma unroll
        for (int nt = 0; nt < 4; ++nt) {
#pragma unroll
            for (int r = 0; r < 4; ++r) {
                out[(rbase + r) * 64 + nt * 16 + m] = acc[nt][r] + bcol[nt];
            }
        }
    }
}

extern "C" void kernel_launch(void* const* d_in, const int* in_sizes, int n_in,
                              void* d_out, int out_size, void* d_ws, size_t ws_size,
                              hipStream_t stream) {
    const float* x      = (const float*)d_in[0];   // 500000 x 8
    const float* weight = (const float*)d_in[1];   // 64 x 164
    const float* bias   = (const float*)d_in[2];   // 64
    float* out          = (float*)d_out;           // 500000 x 64

    dim3 grid(2048), block(256);
    poly_mfma_kernel<<<grid, block, 0, stream>>>(x, weight, bias, out);
}